// Round 3
// baseline (498.833 us; speedup 1.0000x reference)
//
#include <hip/hip_runtime.h>
#include <hip/hip_bf16.h>

#define FPS_THREADS 1024
#define PTS_PER_THR 16      // 16384 / 1024

// ---------------------------------------------------------------------------
// helpers
// ---------------------------------------------------------------------------
__device__ inline unsigned long long shfl_down_u64(unsigned long long x, int off) {
    unsigned int lo = (unsigned int)(x & 0xFFFFFFFFull);
    unsigned int hi = (unsigned int)(x >> 32);
    lo = __shfl_down(lo, off, 64);
    hi = __shfl_down(hi, off, 64);
    return (((unsigned long long)hi) << 32) | lo;
}

// ---------------------------------------------------------------------------
// 1. Farthest point sampling: one block per batch, points cached in registers.
//    One barrier per iteration (double-buffered reduction slots); the argmax
//    scan is done redundantly by all threads; centroid coords come from a
//    broadcast global load (L2-resident). Block 0 also zeroes the BN stats
//    accumulators (they must be zero every call; harness doesn't re-poison).
// ---------------------------------------------------------------------------
__global__ __launch_bounds__(FPS_THREADS) void fps_kernel(
        const float* __restrict__ src, int* __restrict__ cp_idx,
        float* __restrict__ out_cp, float* __restrict__ zero_buf, int zero_n,
        int N, int K) {
    const int b = blockIdx.x;
    const int t = threadIdx.x;
    if (b == 0) {
        for (int i = t; i < zero_n; i += FPS_THREADS) zero_buf[i] = 0.f;
    }
    const float* p = src + (size_t)b * N * 3;

    float px[PTS_PER_THR], py[PTS_PER_THR], pz[PTS_PER_THR], dmin[PTS_PER_THR];
#pragma unroll
    for (int i = 0; i < PTS_PER_THR; ++i) {
        int j = i * FPS_THREADS + t;
        px[i] = p[j * 3 + 0];
        py[i] = p[j * 3 + 1];
        pz[i] = p[j * 3 + 2];
        dmin[i] = __builtin_huge_valf();
    }

    __shared__ unsigned long long red[2][FPS_THREADS / 64];

    int far = 0;
    for (int k = 0;; ++k) {
        // broadcast load of current centroid (same address for all lanes)
        const float cx = p[far * 3 + 0];
        const float cy = p[far * 3 + 1];
        const float cz = p[far * 3 + 2];
        if (t == 0) {
            cp_idx[b * K + k] = far;
            out_cp[(b * K + k) * 3 + 0] = cx;
            out_cp[(b * K + k) * 3 + 1] = cy;
            out_cp[(b * K + k) * 3 + 2] = cz;
        }
        if (k == K - 1) break;

        unsigned long long best = 0ull;
#pragma unroll
        for (int i = 0; i < PTS_PER_THR; ++i) {
            float dx = px[i] - cx, dy = py[i] - cy, dz = pz[i] - cz;
            float d = dx * dx + dy * dy + dz * dz;
            dmin[i] = fminf(dmin[i], d);
            unsigned int fb = __float_as_uint(dmin[i]);   // nonneg -> monotonic bits
            unsigned int j = (unsigned int)(i * FPS_THREADS + t);
            unsigned long long pk =
                (((unsigned long long)fb) << 32) | (0xFFFFFFFFu - j); // tie -> smaller j
            best = (pk > best) ? pk : best;
        }
#pragma unroll
        for (int off = 32; off >= 1; off >>= 1) {
            unsigned long long o = shfl_down_u64(best, off);
            best = (o > best) ? o : best;
        }
        if ((t & 63) == 0) red[k & 1][t >> 6] = best;
        __syncthreads();
        unsigned long long bb = red[k & 1][0];
#pragma unroll
        for (int wv = 1; wv < FPS_THREADS / 64; ++wv)
            bb = (red[k & 1][wv] > bb) ? red[k & 1][wv] : bb;
        far = (int)(0xFFFFFFFFu - (unsigned int)(bb & 0xFFFFFFFFull));
    }
}

// ---------------------------------------------------------------------------
// 2. Fused: nearest target per control point + gather MLP input row.
//    One block per (b,k): argmin over M targets, then copy
//    [control_feats | tgt_local_feats] into mlp_in.
// ---------------------------------------------------------------------------
__global__ __launch_bounds__(256) void nn_gather(
        const float* __restrict__ tgt, const float* __restrict__ cp,
        const int* __restrict__ cp_idx,
        const float* __restrict__ src_feats, const float* __restrict__ tgt_feats,
        float* __restrict__ mlp_in, int N, int M, int F) {
    const int bk = blockIdx.x;          // b*K + k
    const int b = bk >> 7;              // K = 128
    const int t = threadIdx.x;
    const float* tp = tgt + (size_t)b * M * 3;

    const float cx = cp[bk * 3 + 0], cy = cp[bk * 3 + 1], cz = cp[bk * 3 + 2];
    const float cp2 = cx * cx + cy * cy + cz * cz;

    unsigned long long best = ~0ull;
    for (int m = t; m < M; m += 256) {
        float tx = tp[m * 3 + 0], ty = tp[m * 3 + 1], tz = tp[m * 3 + 2];
        float tg2 = tx * tx + ty * ty + tz * tz;
        float cross = cx * tx + cy * ty + cz * tz;
        float v = (cp2 + tg2) - 2.0f * cross;
        unsigned int fb = __float_as_uint(v);
        fb = (fb & 0x80000000u) ? ~fb : (fb | 0x80000000u); // order-preserving flip
        unsigned long long pk = (((unsigned long long)fb) << 32) | (unsigned int)m;
        best = (pk < best) ? pk : best;   // min value, tie -> smaller m
    }
#pragma unroll
    for (int off = 32; off >= 1; off >>= 1) {
        unsigned long long o = shfl_down_u64(best, off);
        best = (o < best) ? o : best;
    }
    __shared__ unsigned long long red[4];
    __shared__ int snn;
    if ((t & 63) == 0) red[t >> 6] = best;
    __syncthreads();
    if (t == 0) {
        unsigned long long bb = red[0];
        for (int wv = 1; wv < 4; ++wv) bb = (red[wv] < bb) ? red[wv] : bb;
        snn = (int)(bb & 0xFFFFFFFFull);
    }
    __syncthreads();
    const int nn = snn;

    const float4* a = reinterpret_cast<const float4*>(
        src_feats + ((size_t)b * N + cp_idx[bk]) * F);
    const float4* c = reinterpret_cast<const float4*>(
        tgt_feats + ((size_t)b * M + nn) * F);
    float4* o = reinterpret_cast<float4*>(mlp_in + (size_t)bk * 2 * F);
    o[t] = a[t];            // F/4 = 256 = blockDim
    o[256 + t] = c[t];
}

// ---------------------------------------------------------------------------
// 3. f32 tiled GEMM with bias + fused column sum/sumsq stats (atomics).
//    BM=BN=64, BK=16, 256 threads, 4x4 per thread.
// ---------------------------------------------------------------------------
__global__ __launch_bounds__(256) void gemm_bias_stats(
        const float* __restrict__ A, const float* __restrict__ B,
        const float* __restrict__ bias, float* __restrict__ C,
        float* __restrict__ psum, float* __restrict__ psumsq,
        int M, int N, int K) {
    __shared__ float As[16][68];
    __shared__ float Bs[16][68];
    const int tid = threadIdx.x;
    const int row0 = blockIdx.y * 64;
    const int col0 = blockIdx.x * 64;

    const int tr = (tid >> 4) * 4;      // 0..60
    const int tc = (tid & 15) * 4;      // 0..60
    const int arow = tid >> 2, ak4 = (tid & 3) * 4;
    const int brow = tid >> 4, bc4 = (tid & 15) * 4;

    float acc[4][4];
#pragma unroll
    for (int i = 0; i < 4; ++i)
#pragma unroll
        for (int j = 0; j < 4; ++j) acc[i][j] = 0.f;

    for (int kt = 0; kt < K; kt += 16) {
        float4 av = *reinterpret_cast<const float4*>(
            &A[(size_t)(row0 + arow) * K + kt + ak4]);
        float4 bv = *reinterpret_cast<const float4*>(
            &B[(size_t)(kt + brow) * N + col0 + bc4]);
        __syncthreads();
        As[ak4 + 0][arow] = av.x;
        As[ak4 + 1][arow] = av.y;
        As[ak4 + 2][arow] = av.z;
        As[ak4 + 3][arow] = av.w;
        *reinterpret_cast<float4*>(&Bs[brow][bc4]) = bv;
        __syncthreads();
#pragma unroll
        for (int kk = 0; kk < 16; ++kk) {
            float a0 = As[kk][tr + 0], a1 = As[kk][tr + 1];
            float a2 = As[kk][tr + 2], a3 = As[kk][tr + 3];
            float b0 = Bs[kk][tc + 0], b1 = Bs[kk][tc + 1];
            float b2 = Bs[kk][tc + 2], b3 = Bs[kk][tc + 3];
            acc[0][0] += a0 * b0; acc[0][1] += a0 * b1; acc[0][2] += a0 * b2; acc[0][3] += a0 * b3;
            acc[1][0] += a1 * b0; acc[1][1] += a1 * b1; acc[1][2] += a1 * b2; acc[1][3] += a1 * b3;
            acc[2][0] += a2 * b0; acc[2][1] += a2 * b1; acc[2][2] += a2 * b2; acc[2][3] += a2 * b3;
            acc[3][0] += a3 * b0; acc[3][1] += a3 * b1; acc[3][2] += a3 * b2; acc[3][3] += a3 * b3;
        }
    }

    // bias + store + per-thread column partials
    float cs[4] = {0.f, 0.f, 0.f, 0.f}, css[4] = {0.f, 0.f, 0.f, 0.f};
#pragma unroll
    for (int i = 0; i < 4; ++i) {
        float* crow = &C[(size_t)(row0 + tr + i) * N + col0 + tc];
#pragma unroll
        for (int j = 0; j < 4; ++j) {
            float v = acc[i][j] + bias[col0 + tc + j];
            crow[j] = v;
            cs[j] += v;
            css[j] += v * v;
        }
    }
    // reduce 16 row-groups per column via LDS, then one atomicAdd per column
    __syncthreads();
#pragma unroll
    for (int j = 0; j < 4; ++j) {
        As[tid >> 4][tc + j] = cs[j];
        Bs[tid >> 4][tc + j] = css[j];
    }
    __syncthreads();
    if (tid < 64) {
        float s = 0.f, ss = 0.f;
#pragma unroll
        for (int r = 0; r < 16; ++r) { s += As[r][tid]; ss += Bs[r][tid]; }
        atomicAdd(&psum[col0 + tid], s);
        atomicAdd(&psumsq[col0 + tid], ss);
    }
}

// ---------------------------------------------------------------------------
// 4. BN apply + ReLU (in place), stats computed from psum/psumsq directly
// ---------------------------------------------------------------------------
__global__ __launch_bounds__(256) void bn_apply_p(
        float* __restrict__ Hm, const float* __restrict__ psum,
        const float* __restrict__ psumsq, const float* __restrict__ g,
        const float* __restrict__ beta, int total, int NcolsMask, float invM) {
    const int i = blockIdx.x * 256 + threadIdx.x;
    if (i < total) {
        const int c = i & NcolsMask;
        const float m = psum[c] * invM;
        const float var = fmaxf(psumsq[c] * invM - m * m, 0.f);
        const float rs = rsqrtf(var + 1e-5f);
        float x = Hm[i];
        x = g[c] * (x - m) * rs + beta[c];
        Hm[i] = fmaxf(x, 0.f);
    }
}

// ---------------------------------------------------------------------------
// 5. Fused BN2 + head: w (1024x3) = relu(bn(h2)) @ W3 + b3 ; one block per row
// ---------------------------------------------------------------------------
__global__ __launch_bounds__(256) void bn_head(
        const float* __restrict__ H2, const float* __restrict__ psum,
        const float* __restrict__ psumsq, const float* __restrict__ g,
        const float* __restrict__ beta, const float* __restrict__ W3,
        const float* __restrict__ b3, float* __restrict__ w_out,
        int Ncols, float invM) {
    const int r = blockIdx.x;
    const int t = threadIdx.x;
    float a0 = 0.f, a1 = 0.f, a2 = 0.f;
    for (int c = t; c < Ncols; c += 256) {
        const float m = psum[c] * invM;
        const float var = fmaxf(psumsq[c] * invM - m * m, 0.f);
        const float rs = rsqrtf(var + 1e-5f);
        float x = H2[(size_t)r * Ncols + c];
        float h = fmaxf(g[c] * (x - m) * rs + beta[c], 0.f);
        a0 += h * W3[c * 3 + 0];
        a1 += h * W3[c * 3 + 1];
        a2 += h * W3[c * 3 + 2];
    }
#pragma unroll
    for (int off = 32; off >= 1; off >>= 1) {
        a0 += __shfl_down(a0, off, 64);
        a1 += __shfl_down(a1, off, 64);
        a2 += __shfl_down(a2, off, 64);
    }
    __shared__ float red[4][3];
    if ((t & 63) == 0) {
        red[t >> 6][0] = a0; red[t >> 6][1] = a1; red[t >> 6][2] = a2;
    }
    __syncthreads();
    if (t == 0) {
        float s0 = red[0][0] + red[1][0] + red[2][0] + red[3][0];
        float s1 = red[0][1] + red[1][1] + red[2][1] + red[3][1];
        float s2 = red[0][2] + red[1][2] + red[2][2] + red[3][2];
        w_out[r * 3 + 0] = s0 + b3[0];
        w_out[r * 3 + 1] = s1 + b3[1];
        w_out[r * 3 + 2] = s2 + b3[2];
    }
}

// ---------------------------------------------------------------------------
// 6. RBF softmax interpolation: output = src + (softmax(-2*d2) @ w)
// ---------------------------------------------------------------------------
__global__ __launch_bounds__(256) void rbf_kernel(
        const float* __restrict__ src, const float* __restrict__ cp,
        const float* __restrict__ w, float* __restrict__ outp,
        float* __restrict__ delta, int N, int K) {
    __shared__ float scx[128], scy[128], scz[128];
    __shared__ float swx[128], swy[128], swz[128];
    const int b = blockIdx.x >> 6;      // 64 chunks of 256 per batch
    const int chunk = blockIdx.x & 63;
    const int t = threadIdx.x;
    if (t < K) {
        const int base = (b * K + t) * 3;
        scx[t] = cp[base + 0]; scy[t] = cp[base + 1]; scz[t] = cp[base + 2];
        swx[t] = w[base + 0];  swy[t] = w[base + 1];  swz[t] = w[base + 2];
    }
    __syncthreads();

    const int n = chunk * 256 + t;
    const size_t pbase = ((size_t)b * N + n) * 3;
    const float x = src[pbase + 0], y = src[pbase + 1], z = src[pbase + 2];

    float mind = __builtin_huge_valf();
    for (int k = 0; k < K; ++k) {
        float dx = x - scx[k], dy = y - scy[k], dz = z - scz[k];
        float d2 = dx * dx + dy * dy + dz * dz;
        mind = fminf(mind, d2);
    }
    float sum = 0.f, ax = 0.f, ay = 0.f, az = 0.f;
    for (int k = 0; k < K; ++k) {
        float dx = x - scx[k], dy = y - scy[k], dz = z - scz[k];
        float d2 = dx * dx + dy * dy + dz * dz;
        float e = __expf(2.0f * (mind - d2));   // softmax(-2*d2), max-subtracted
        sum += e;
        ax += e * swx[k]; ay += e * swy[k]; az += e * swz[k];
    }
    const float inv = 1.0f / sum;
    ax *= inv; ay *= inv; az *= inv;
    delta[pbase + 0] = ax; delta[pbase + 1] = ay; delta[pbase + 2] = az;
    outp[pbase + 0] = x + ax; outp[pbase + 1] = y + ay; outp[pbase + 2] = z + az;
}

// ---------------------------------------------------------------------------
// launch
// ---------------------------------------------------------------------------
extern "C" void kernel_launch(void* const* d_in, const int* in_sizes, int n_in,
                              void* d_out, int out_size, void* d_ws, size_t ws_size,
                              hipStream_t stream) {
    const int B = 8, N = 16384, M = 16384, F = 1024, H = 512, K = 128;
    const int BK = B * K;               // 1024 MLP rows

    const float* src       = (const float*)d_in[0];
    const float* ppf       = (const float*)d_in[1];
    const float* tgt       = (const float*)d_in[2];
    const float* tpf       = (const float*)d_in[3];
    const float* W1        = (const float*)d_in[4];
    const float* b1        = (const float*)d_in[5];
    const float* g1        = (const float*)d_in[6];
    const float* beta1     = (const float*)d_in[7];
    const float* W2        = (const float*)d_in[8];
    const float* b2        = (const float*)d_in[9];
    const float* g2        = (const float*)d_in[10];
    const float* beta2     = (const float*)d_in[11];
    const float* W3        = (const float*)d_in[12];
    const float* b3        = (const float*)d_in[13];

    float* out_output = (float*)d_out;                       // B*N*3
    float* out_delta  = out_output + (size_t)B * N * 3;      // B*N*3
    float* out_cp     = out_delta + (size_t)B * N * 3;       // B*K*3
    float* out_w      = out_cp + (size_t)B * K * 3;          // B*K*3

    char* ws = (char*)d_ws;
    int*   cp_idx  = (int*)(ws + 0);                         // 4 KB
    float* stats   = (float*)(ws + 4096);                    // 2048 floats (8 KB)
    float* psum1   = stats;                                  // 512
    float* psumsq1 = stats + 512;
    float* psum2   = stats + 1024;
    float* psumsq2 = stats + 1536;
    float* mlp_in  = (float*)(ws + 16384);                           // 1024 x 2048 (8 MB)
    float* h1      = (float*)(ws + 16384 + (size_t)BK * 2 * F * 4);  // 1024 x 512  (2 MB)
    float* h2      = (float*)((char*)h1 + (size_t)BK * H * 4);       // 1024 x 512  (2 MB)

    // 1. FPS (also zeroes the 2048-float stats region before the GEMMs)
    fps_kernel<<<B, FPS_THREADS, 0, stream>>>(src, cp_idx, out_cp, stats, 2048, N, K);
    // 2. fused nearest-target + gather
    nn_gather<<<BK, 256, 0, stream>>>(tgt, out_cp, cp_idx, ppf, tpf, mlp_in, N, M, F);
    // 3. layer 1: GEMM + bias + column stats, then BN apply
    gemm_bias_stats<<<dim3(H / 64, BK / 64), 256, 0, stream>>>(
        mlp_in, W1, b1, h1, psum1, psumsq1, BK, H, 2 * F);
    bn_apply_p<<<(BK * H + 255) / 256, 256, 0, stream>>>(
        h1, psum1, psumsq1, g1, beta1, BK * H, H - 1, 1.0f / BK);
    // 4. layer 2: GEMM + bias + column stats, then fused BN + head -> w
    gemm_bias_stats<<<dim3(H / 64, BK / 64), 256, 0, stream>>>(
        h1, W2, b2, h2, psum2, psumsq2, BK, H, H);
    bn_head<<<BK, 256, 0, stream>>>(
        h2, psum2, psumsq2, g2, beta2, W3, b3, out_w, H, 1.0f / BK);
    // 5. RBF interpolation -> output, delta
    rbf_kernel<<<B * (N / 256), 256, 0, stream>>>(src, out_cp, out_w, out_output, out_delta, N, K);
}

// Round 4
// 427.803 us; speedup vs baseline: 1.1660x; 1.1660x over previous
//
#include <hip/hip_runtime.h>
#include <hip/hip_bf16.h>

#define FPS_THREADS 1024
#define PTS_PER_THR 16      // 16384 / 1024
#define CONV_BLOCKS 120

typedef __attribute__((ext_vector_type(8))) short bf16x8;
typedef __attribute__((ext_vector_type(4))) float f32x4;

// ---------------------------------------------------------------------------
// helpers
// ---------------------------------------------------------------------------
__device__ inline unsigned long long shfl_down_u64(unsigned long long x, int off) {
    unsigned int lo = (unsigned int)(x & 0xFFFFFFFFull);
    unsigned int hi = (unsigned int)(x >> 32);
    lo = __shfl_down(lo, off, 64);
    hi = __shfl_down(hi, off, 64);
    return (((unsigned long long)hi) << 32) | lo;
}

__device__ inline unsigned short f2bf(float x) {
    union { float f; unsigned int u; } v; v.f = x;
    unsigned int r = v.u + 0x7FFFu + ((v.u >> 16) & 1u);   // round-to-nearest-even
    return (unsigned short)(r >> 16);
}

// ---------------------------------------------------------------------------
// 1. FPS (blocks 0..7, one per batch) + weight transpose/convert + stats zero
//    (blocks 8..127, runs in the shadow of the serial FPS).
// ---------------------------------------------------------------------------
__global__ __launch_bounds__(FPS_THREADS) void fps_conv_kernel(
        const float* __restrict__ src, int* __restrict__ cp_idx,
        float* __restrict__ out_cp,
        const float* __restrict__ W1, const float* __restrict__ W2,
        unsigned short* __restrict__ W1t, unsigned short* __restrict__ W2t,
        float* __restrict__ stats, int N, int K) {
    const int t = threadIdx.x;
    if (blockIdx.x >= 8) {
        const int cb = blockIdx.x - 8;
        if (cb == 0) { stats[t] = 0.f; stats[t + 1024] = 0.f; }  // 2048 floats
        // W1t[n][k] = bf16(W1[k][n]);  W1: (2048, 512)
        for (size_t idx = (size_t)cb * 1024 + t; idx < (size_t)2048 * 512;
             idx += (size_t)CONV_BLOCKS * 1024) {
            int k = (int)(idx >> 9), n = (int)(idx & 511);
            W1t[(size_t)n * 2048 + k] = f2bf(W1[idx]);
        }
        // W2t[n][k] = bf16(W2[k][n]);  W2: (512, 512)
        for (size_t idx = (size_t)cb * 1024 + t; idx < (size_t)512 * 512;
             idx += (size_t)CONV_BLOCKS * 1024) {
            int k = (int)(idx >> 9), n = (int)(idx & 511);
            W2t[(size_t)n * 512 + k] = f2bf(W2[idx]);
        }
        return;
    }

    const int b = blockIdx.x;
    const float* p = src + (size_t)b * N * 3;

    float px[PTS_PER_THR], py[PTS_PER_THR], pz[PTS_PER_THR], dmin[PTS_PER_THR];
#pragma unroll
    for (int i = 0; i < PTS_PER_THR; ++i) {
        int j = i * FPS_THREADS + t;
        px[i] = p[j * 3 + 0];
        py[i] = p[j * 3 + 1];
        pz[i] = p[j * 3 + 2];
        dmin[i] = __builtin_huge_valf();
    }

    __shared__ unsigned long long red[2][FPS_THREADS / 64];

    int far = 0;
    for (int k = 0;; ++k) {
        const float cx = p[far * 3 + 0];
        const float cy = p[far * 3 + 1];
        const float cz = p[far * 3 + 2];
        if (t == 0) {
            cp_idx[b * K + k] = far;
            out_cp[(b * K + k) * 3 + 0] = cx;
            out_cp[(b * K + k) * 3 + 1] = cy;
            out_cp[(b * K + k) * 3 + 2] = cz;
        }
        if (k == K - 1) break;

        unsigned long long best = 0ull;
#pragma unroll
        for (int i = 0; i < PTS_PER_THR; ++i) {
            float dx = px[i] - cx, dy = py[i] - cy, dz = pz[i] - cz;
            float d = dx * dx + dy * dy + dz * dz;
            dmin[i] = fminf(dmin[i], d);
            unsigned int fb = __float_as_uint(dmin[i]);   // nonneg -> monotonic bits
            unsigned int j = (unsigned int)(i * FPS_THREADS + t);
            unsigned long long pk =
                (((unsigned long long)fb) << 32) | (0xFFFFFFFFu - j); // tie -> smaller j
            best = (pk > best) ? pk : best;
        }
#pragma unroll
        for (int off = 32; off >= 1; off >>= 1) {
            unsigned long long o = shfl_down_u64(best, off);
            best = (o > best) ? o : best;
        }
        if ((t & 63) == 0) red[k & 1][t >> 6] = best;
        __syncthreads();
        unsigned long long bb = red[k & 1][0];
#pragma unroll
        for (int wv = 1; wv < FPS_THREADS / 64; ++wv)
            bb = (red[k & 1][wv] > bb) ? red[k & 1][wv] : bb;
        far = (int)(0xFFFFFFFFu - (unsigned int)(bb & 0xFFFFFFFFull));
    }
}

// ---------------------------------------------------------------------------
// 2. Fused: nearest target per control point + gather MLP input row (bf16).
// ---------------------------------------------------------------------------
__global__ __launch_bounds__(256) void nn_gather(
        const float* __restrict__ tgt, const float* __restrict__ cp,
        const int* __restrict__ cp_idx,
        const float* __restrict__ src_feats, const float* __restrict__ tgt_feats,
        unsigned short* __restrict__ mlp_b, int N, int M, int F) {
    const int bk = blockIdx.x;          // b*K + k
    const int b = bk >> 7;              // K = 128
    const int t = threadIdx.x;
    const float* tp = tgt + (size_t)b * M * 3;

    const float cx = cp[bk * 3 + 0], cy = cp[bk * 3 + 1], cz = cp[bk * 3 + 2];
    const float cp2 = cx * cx + cy * cy + cz * cz;

    unsigned long long best = ~0ull;
    for (int m = t; m < M; m += 256) {
        float tx = tp[m * 3 + 0], ty = tp[m * 3 + 1], tz = tp[m * 3 + 2];
        float tg2 = tx * tx + ty * ty + tz * tz;
        float cross = cx * tx + cy * ty + cz * tz;
        float v = (cp2 + tg2) - 2.0f * cross;
        unsigned int fb = __float_as_uint(v);
        fb = (fb & 0x80000000u) ? ~fb : (fb | 0x80000000u); // order-preserving flip
        unsigned long long pk = (((unsigned long long)fb) << 32) | (unsigned int)m;
        best = (pk < best) ? pk : best;   // min value, tie -> smaller m
    }
#pragma unroll
    for (int off = 32; off >= 1; off >>= 1) {
        unsigned long long o = shfl_down_u64(best, off);
        best = (o < best) ? o : best;
    }
    __shared__ unsigned long long red[4];
    __shared__ int snn;
    if ((t & 63) == 0) red[t >> 6] = best;
    __syncthreads();
    if (t == 0) {
        unsigned long long bb = red[0];
        for (int wv = 1; wv < 4; ++wv) bb = (red[wv] < bb) ? red[wv] : bb;
        snn = (int)(bb & 0xFFFFFFFFull);
    }
    __syncthreads();
    const int nn = snn;

    const float4* a = reinterpret_cast<const float4*>(
        src_feats + ((size_t)b * N + cp_idx[bk]) * F);
    const float4* c = reinterpret_cast<const float4*>(
        tgt_feats + ((size_t)b * M + nn) * F);
    unsigned short* o = mlp_b + (size_t)bk * 2 * F;
    float4 av = a[t];
    float4 cv = c[t];
    ushort4 a4, c4;
    a4.x = f2bf(av.x); a4.y = f2bf(av.y); a4.z = f2bf(av.z); a4.w = f2bf(av.w);
    c4.x = f2bf(cv.x); c4.y = f2bf(cv.y); c4.z = f2bf(cv.z); c4.w = f2bf(cv.w);
    *reinterpret_cast<ushort4*>(&o[t * 4]) = a4;            // cols [0,1024)
    *reinterpret_cast<ushort4*>(&o[F + t * 4]) = c4;        // cols [1024,2048)
}

// ---------------------------------------------------------------------------
// 3. bf16 MFMA GEMM + bias + fused column sum/sumsq stats.
//    C(MxN f32) = A(MxK bf16, row-major) @ Bt(NxK bf16, transposed) + bias.
//    64x64 tile, 256 threads (4 waves), mfma_f32_16x16x32_bf16.
//    Wave w computes rows [w*16, w*16+16) x all 64 cols (4 n-tiles).
// ---------------------------------------------------------------------------
__global__ __launch_bounds__(256) void gemm_mfma_stats(
        const unsigned short* __restrict__ A, const unsigned short* __restrict__ Bt,
        const float* __restrict__ bias, float* __restrict__ C,
        float* __restrict__ psum, float* __restrict__ psumsq,
        int M, int N, int K) {
    __shared__ __align__(16) unsigned short As[64][72];
    __shared__ __align__(16) unsigned short Bs[64][72];
    __shared__ float sS[64], sSS[64];
    const int tid = threadIdx.x;
    const int w = tid >> 6, l = tid & 63;
    const int m0 = blockIdx.y * 64, n0 = blockIdx.x * 64;

    f32x4 acc[4];
#pragma unroll
    for (int nt = 0; nt < 4; ++nt) acc[nt] = (f32x4){0.f, 0.f, 0.f, 0.f};

    const int lr = l & 15;        // row/col within 16-tile
    const int lg = l >> 4;        // k-group 0..3

    for (int kt = 0; kt < K; kt += 64) {
        __syncthreads();
#pragma unroll
        for (int s = 0; s < 2; ++s) {
            int u = tid + s * 256;
            int row = u >> 3, kc = (u & 7) * 8;
            *reinterpret_cast<uint4*>(&As[row][kc]) =
                *reinterpret_cast<const uint4*>(&A[(size_t)(m0 + row) * K + kt + kc]);
            *reinterpret_cast<uint4*>(&Bs[row][kc]) =
                *reinterpret_cast<const uint4*>(&Bt[(size_t)(n0 + row) * K + kt + kc]);
        }
        __syncthreads();
#pragma unroll
        for (int kf = 0; kf < 2; ++kf) {
            bf16x8 af = *reinterpret_cast<const bf16x8*>(&As[w * 16 + lr][kf * 32 + lg * 8]);
#pragma unroll
            for (int nt = 0; nt < 4; ++nt) {
                bf16x8 bfr = *reinterpret_cast<const bf16x8*>(&Bs[nt * 16 + lr][kf * 32 + lg * 8]);
                acc[nt] = __builtin_amdgcn_mfma_f32_16x16x32_bf16(af, bfr, acc[nt], 0, 0, 0);
            }
        }
    }

    // epilogue: bias add, C store, column stats
    if (tid < 64) { sS[tid] = 0.f; sSS[tid] = 0.f; }
    __syncthreads();
#pragma unroll
    for (int nt = 0; nt < 4; ++nt) {
        const int col = n0 + nt * 16 + lr;
        const float bv = bias[col];
        float s = 0.f, ss = 0.f;
#pragma unroll
        for (int r = 0; r < 4; ++r) {
            const int row = m0 + w * 16 + lg * 4 + r;     // C/D: row=(lane>>4)*4+reg
            float v = acc[nt][r] + bv;
            C[(size_t)row * N + col] = v;
            s += v; ss += v * v;
        }
        s += __shfl_xor(s, 16, 64); ss += __shfl_xor(ss, 16, 64);
        s += __shfl_xor(s, 32, 64); ss += __shfl_xor(ss, 32, 64);
        if (lg == 0) {                                     // lanes 0..15 of each wave
            atomicAdd(&sS[nt * 16 + lr], s);
            atomicAdd(&sSS[nt * 16 + lr], ss);
        }
    }
    __syncthreads();
    if (tid < 64) {
        atomicAdd(&psum[n0 + tid], sS[tid]);
        atomicAdd(&psumsq[n0 + tid], sSS[tid]);
    }
}

// ---------------------------------------------------------------------------
// 4. BN apply + ReLU: h1 (f32) -> h1b (bf16) for layer-2 GEMM
// ---------------------------------------------------------------------------
__global__ __launch_bounds__(256) void bn_apply_bf16(
        const float* __restrict__ Hm, const float* __restrict__ psum,
        const float* __restrict__ psumsq, const float* __restrict__ g,
        const float* __restrict__ beta, unsigned short* __restrict__ out,
        float invM) {
    const int i = (blockIdx.x * 256 + threadIdx.x) * 4;
    float4 x = *reinterpret_cast<const float4*>(&Hm[i]);
    const int c = i & 511;                 // H = 512
    ushort4 o4;
    float xv[4] = {x.x, x.y, x.z, x.w};
    unsigned short ov[4];
#pragma unroll
    for (int j = 0; j < 4; ++j) {
        const int col = c + j;
        const float m = psum[col] * invM;
        const float var = fmaxf(psumsq[col] * invM - m * m, 0.f);
        const float rs = rsqrtf(var + 1e-5f);
        float h = fmaxf(g[col] * (xv[j] - m) * rs + beta[col], 0.f);
        ov[j] = f2bf(h);
    }
    o4.x = ov[0]; o4.y = ov[1]; o4.z = ov[2]; o4.w = ov[3];
    *reinterpret_cast<ushort4*>(&out[i]) = o4;
}

// ---------------------------------------------------------------------------
// 5. Fused BN2 + head: w (1024x3) = relu(bn(h2)) @ W3 + b3 ; one block per row
// ---------------------------------------------------------------------------
__global__ __launch_bounds__(256) void bn_head(
        const float* __restrict__ H2, const float* __restrict__ psum,
        const float* __restrict__ psumsq, const float* __restrict__ g,
        const float* __restrict__ beta, const float* __restrict__ W3,
        const float* __restrict__ b3, float* __restrict__ w_out,
        int Ncols, float invM) {
    const int r = blockIdx.x;
    const int t = threadIdx.x;
    float a0 = 0.f, a1 = 0.f, a2 = 0.f;
    for (int c = t; c < Ncols; c += 256) {
        const float m = psum[c] * invM;
        const float var = fmaxf(psumsq[c] * invM - m * m, 0.f);
        const float rs = rsqrtf(var + 1e-5f);
        float x = H2[(size_t)r * Ncols + c];
        float h = fmaxf(g[c] * (x - m) * rs + beta[c], 0.f);
        a0 += h * W3[c * 3 + 0];
        a1 += h * W3[c * 3 + 1];
        a2 += h * W3[c * 3 + 2];
    }
#pragma unroll
    for (int off = 32; off >= 1; off >>= 1) {
        a0 += __shfl_down(a0, off, 64);
        a1 += __shfl_down(a1, off, 64);
        a2 += __shfl_down(a2, off, 64);
    }
    __shared__ float red[4][3];
    if ((t & 63) == 0) {
        red[t >> 6][0] = a0; red[t >> 6][1] = a1; red[t >> 6][2] = a2;
    }
    __syncthreads();
    if (t == 0) {
        float s0 = red[0][0] + red[1][0] + red[2][0] + red[3][0];
        float s1 = red[0][1] + red[1][1] + red[2][1] + red[3][1];
        float s2 = red[0][2] + red[1][2] + red[2][2] + red[3][2];
        w_out[r * 3 + 0] = s0 + b3[0];
        w_out[r * 3 + 1] = s1 + b3[1];
        w_out[r * 3 + 2] = s2 + b3[2];
    }
}

// ---------------------------------------------------------------------------
// 6. RBF softmax interpolation: output = src + (softmax(-2*d2) @ w)
// ---------------------------------------------------------------------------
__global__ __launch_bounds__(256) void rbf_kernel(
        const float* __restrict__ src, const float* __restrict__ cp,
        const float* __restrict__ w, float* __restrict__ outp,
        float* __restrict__ delta, int N, int K) {
    __shared__ float scx[128], scy[128], scz[128];
    __shared__ float swx[128], swy[128], swz[128];
    const int b = blockIdx.x >> 6;      // 64 chunks of 256 per batch
    const int chunk = blockIdx.x & 63;
    const int t = threadIdx.x;
    if (t < K) {
        const int base = (b * K + t) * 3;
        scx[t] = cp[base + 0]; scy[t] = cp[base + 1]; scz[t] = cp[base + 2];
        swx[t] = w[base + 0];  swy[t] = w[base + 1];  swz[t] = w[base + 2];
    }
    __syncthreads();

    const int n = chunk * 256 + t;
    const size_t pbase = ((size_t)b * N + n) * 3;
    const float x = src[pbase + 0], y = src[pbase + 1], z = src[pbase + 2];

    float mind = __builtin_huge_valf();
    for (int k = 0; k < K; ++k) {
        float dx = x - scx[k], dy = y - scy[k], dz = z - scz[k];
        float d2 = dx * dx + dy * dy + dz * dz;
        mind = fminf(mind, d2);
    }
    float sum = 0.f, ax = 0.f, ay = 0.f, az = 0.f;
    for (int k = 0; k < K; ++k) {
        float dx = x - scx[k], dy = y - scy[k], dz = z - scz[k];
        float d2 = dx * dx + dy * dy + dz * dz;
        float e = __expf(2.0f * (mind - d2));   // softmax(-2*d2), max-subtracted
        sum += e;
        ax += e * swx[k]; ay += e * swy[k]; az += e * swz[k];
    }
    const float inv = 1.0f / sum;
    ax *= inv; ay *= inv; az *= inv;
    delta[pbase + 0] = ax; delta[pbase + 1] = ay; delta[pbase + 2] = az;
    outp[pbase + 0] = x + ax; outp[pbase + 1] = y + ay; outp[pbase + 2] = z + az;
}

// ---------------------------------------------------------------------------
// launch
// ---------------------------------------------------------------------------
extern "C" void kernel_launch(void* const* d_in, const int* in_sizes, int n_in,
                              void* d_out, int out_size, void* d_ws, size_t ws_size,
                              hipStream_t stream) {
    const int B = 8, N = 16384, M = 16384, F = 1024, H = 512, K = 128;
    const int BK = B * K;               // 1024 MLP rows

    const float* src       = (const float*)d_in[0];
    const float* ppf       = (const float*)d_in[1];
    const float* tgt       = (const float*)d_in[2];
    const float* tpf       = (const float*)d_in[3];
    const float* W1        = (const float*)d_in[4];
    const float* b1        = (const float*)d_in[5];
    const float* g1        = (const float*)d_in[6];
    const float* beta1     = (const float*)d_in[7];
    const float* W2        = (const float*)d_in[8];
    const float* b2        = (const float*)d_in[9];
    const float* g2        = (const float*)d_in[10];
    const float* beta2     = (const float*)d_in[11];
    const float* W3        = (const float*)d_in[12];
    const float* b3        = (const float*)d_in[13];

    float* out_output = (float*)d_out;                       // B*N*3
    float* out_delta  = out_output + (size_t)B * N * 3;      // B*N*3
    float* out_cp     = out_delta + (size_t)B * N * 3;       // B*K*3
    float* out_w      = out_cp + (size_t)B * K * 3;          // B*K*3

    char* ws = (char*)d_ws;
    int*            cp_idx = (int*)(ws + 0);                 // 4 KB
    float*          stats  = (float*)(ws + 4096);            // 2048 floats (8 KB)
    float* psum1   = stats;
    float* psumsq1 = stats + 512;
    float* psum2   = stats + 1024;
    float* psumsq2 = stats + 1536;
    unsigned short* mlp_b  = (unsigned short*)(ws + 16384);       // 1024x2048 bf16 (4 MB)
    unsigned short* W1t    = (unsigned short*)(ws + 4210688);     // 512x2048 bf16 (2 MB)
    unsigned short* W2t    = (unsigned short*)(ws + 6307840);     // 512x512 bf16 (512 KB)
    float*          h1     = (float*)(ws + 6832128);              // 1024x512 f32 (2 MB)
    unsigned short* h1b    = (unsigned short*)(ws + 8929280);     // 1024x512 bf16 (1 MB)
    float*          h2     = (float*)(ws + 9977856);              // 1024x512 f32 (2 MB)

    // 1. FPS + weight convert/transpose + stats zero
    fps_conv_kernel<<<8 + CONV_BLOCKS, FPS_THREADS, 0, stream>>>(
        src, cp_idx, out_cp, W1, W2, W1t, W2t, stats, N, K);
    // 2. fused nearest-target + gather (bf16)
    nn_gather<<<BK, 256, 0, stream>>>(tgt, out_cp, cp_idx, ppf, tpf, mlp_b, N, M, F);
    // 3. layer 1: MFMA GEMM + bias + stats
    gemm_mfma_stats<<<dim3(H / 64, BK / 64), 256, 0, stream>>>(
        mlp_b, W1t, b1, h1, psum1, psumsq1, BK, H, 2 * F);
    // 4. BN1 apply -> bf16
    bn_apply_bf16<<<(BK * H / 4) / 256, 256, 0, stream>>>(
        h1, psum1, psumsq1, g1, beta1, h1b, 1.0f / BK);
    // 5. layer 2: MFMA GEMM + bias + stats
    gemm_mfma_stats<<<dim3(H / 64, BK / 64), 256, 0, stream>>>(
        h1b, W2t, b2, h2, psum2, psumsq2, BK, H, H);
    // 6. fused BN2 + head -> w
    bn_head<<<BK, 256, 0, stream>>>(
        h2, psum2, psumsq2, g2, beta2, W3, b3, out_w, H, 1.0f / BK);
    // 7. RBF interpolation -> output, delta
    rbf_kernel<<<B * (N / 256), 256, 0, stream>>>(src, out_cp, out_w, out_output, out_delta, N, K);
}

// Round 5
// 369.852 us; speedup vs baseline: 1.3487x; 1.1567x over previous
//
#include <hip/hip_runtime.h>
#include <hip/hip_bf16.h>

#define FPS_THREADS 1024
#define PTS_PER_THR 16      // 16384 / 1024
#define CONV_BLOCKS 120

typedef __attribute__((ext_vector_type(8))) short bf16x8;
typedef __attribute__((ext_vector_type(4))) float f32x4;

// ---------------------------------------------------------------------------
// helpers
// ---------------------------------------------------------------------------
__device__ inline unsigned long long shfl_down_u64(unsigned long long x, int off) {
    unsigned int lo = (unsigned int)(x & 0xFFFFFFFFull);
    unsigned int hi = (unsigned int)(x >> 32);
    lo = __shfl_down(lo, off, 64);
    hi = __shfl_down(hi, off, 64);
    return (((unsigned long long)hi) << 32) | lo;
}

__device__ inline unsigned short f2bf(float x) {
    union { float f; unsigned int u; } v; v.f = x;
    unsigned int r = v.u + 0x7FFFu + ((v.u >> 16) & 1u);   // round-to-nearest-even
    return (unsigned short)(r >> 16);
}

// ---------------------------------------------------------------------------
// 1. FPS (blocks 0..7, one per batch) + weight transpose/convert + stats zero
//    (blocks 8..127, runs in the shadow of the serial FPS).
//
//    FPS per iteration: per-thread (tmax,jbest) argmax with strict > (keeps
//    first max = smallest index, matching numpy argmax); wave reduce = 6 f32
//    shfl_xor max levels; index resolved via ballot + scalar min-j loop
//    (exact ties); cross-wave via ds_max_u64 atomic on a 3-slot rotating
//    LDS cell (slot m is reset two iterations after its last read -> no race).
// ---------------------------------------------------------------------------
__global__ __launch_bounds__(FPS_THREADS) void fps_conv_kernel(
        const float* __restrict__ src, int* __restrict__ cp_idx,
        float* __restrict__ out_cp,
        const float* __restrict__ W1, const float* __restrict__ W2,
        unsigned short* __restrict__ W1t, unsigned short* __restrict__ W2t,
        float* __restrict__ stats, int N, int K) {
    const int t = threadIdx.x;
    if (blockIdx.x >= 8) {
        const int cb = blockIdx.x - 8;
        if (cb == 0) { stats[t] = 0.f; stats[t + 1024] = 0.f; }  // 2048 floats
        // W1t[n][k] = bf16(W1[k][n]);  W1: (2048, 512)
        for (size_t idx = (size_t)cb * 1024 + t; idx < (size_t)2048 * 512;
             idx += (size_t)CONV_BLOCKS * 1024) {
            int k = (int)(idx >> 9), n = (int)(idx & 511);
            W1t[(size_t)n * 2048 + k] = f2bf(W1[idx]);
        }
        // W2t[n][k] = bf16(W2[k][n]);  W2: (512, 512)
        for (size_t idx = (size_t)cb * 1024 + t; idx < (size_t)512 * 512;
             idx += (size_t)CONV_BLOCKS * 1024) {
            int k = (int)(idx >> 9), n = (int)(idx & 511);
            W2t[(size_t)n * 512 + k] = f2bf(W2[idx]);
        }
        return;
    }

    const int b = blockIdx.x;
    const float* p = src + (size_t)b * N * 3;

    float px[PTS_PER_THR], py[PTS_PER_THR], pz[PTS_PER_THR], dmin[PTS_PER_THR];
#pragma unroll
    for (int i = 0; i < PTS_PER_THR; ++i) {
        int j = i * FPS_THREADS + t;
        px[i] = p[j * 3 + 0];
        py[i] = p[j * 3 + 1];
        pz[i] = p[j * 3 + 2];
        dmin[i] = __builtin_huge_valf();
    }

    __shared__ unsigned long long slot[3];
    if (t == 0) { slot[0] = 0ull; slot[1] = 0ull; slot[2] = 0ull; }
    __syncthreads();

    int far = 0;
    int cur = 0;
    for (int k = 0;; ++k) {
        const float cx = p[far * 3 + 0];
        const float cy = p[far * 3 + 1];
        const float cz = p[far * 3 + 2];
        if (t == 0) {
            cp_idx[b * K + k] = far;
            out_cp[(b * K + k) * 3 + 0] = cx;
            out_cp[(b * K + k) * 3 + 1] = cy;
            out_cp[(b * K + k) * 3 + 2] = cz;
        }
        if (k == K - 1) break;

        // update dmin; per-thread argmax (strict > keeps first = smallest j)
        float tmax = -1.0f;
        int jbest = 0;
#pragma unroll
        for (int i = 0; i < PTS_PER_THR; ++i) {
            float dx = px[i] - cx, dy = py[i] - cy, dz = pz[i] - cz;
            float d = dx * dx + dy * dy + dz * dz;
            float dm = fminf(dmin[i], d);
            dmin[i] = dm;
            bool c = dm > tmax;
            tmax = c ? dm : tmax;
            jbest = c ? (i * FPS_THREADS + t) : jbest;
        }

        // wave max (f32 only, 6 levels)
        float w = tmax;
#pragma unroll
        for (int off = 32; off >= 1; off >>= 1)
            w = fmaxf(w, __shfl_xor(w, off, 64));

        // resolve smallest index among tied lanes (usually 1 lane)
        unsigned long long mask = __ballot(tmax == w);
        int jw = 0x7FFFFFFF;
        while (mask) {
            int l = __ffsll((unsigned long long)mask) - 1;
            int jv = __shfl(jbest, l, 64);
            jw = jv < jw ? jv : jw;
            mask &= mask - 1;
        }

        // publish wave result: packed (value || ~j) so bigger = better,
        // tie -> smaller j. One ds_max_u64 per wave.
        if ((t & 63) == 0) {
            unsigned long long pk =
                (((unsigned long long)__float_as_uint(w)) << 32) |
                (unsigned long long)(0xFFFFFFFFu - (unsigned int)jw);
            atomicMax(&slot[cur], pk);
        }
        const int nxt = (cur == 2) ? 0 : cur + 1;
        if (t == 0) slot[nxt] = 0ull;   // reset for iteration k+1 (safe: last
                                        // read of this slot was in iter k-2)
        __syncthreads();
        unsigned long long bb = slot[cur];
        far = (int)(0xFFFFFFFFu - (unsigned int)(bb & 0xFFFFFFFFull));
        cur = nxt;
    }
}

// ---------------------------------------------------------------------------
// 2. Fused: nearest target per control point + gather MLP input row (bf16).
// ---------------------------------------------------------------------------
__global__ __launch_bounds__(256) void nn_gather(
        const float* __restrict__ tgt, const float* __restrict__ cp,
        const int* __restrict__ cp_idx,
        const float* __restrict__ src_feats, const float* __restrict__ tgt_feats,
        unsigned short* __restrict__ mlp_b, int N, int M, int F) {
    const int bk = blockIdx.x;          // b*K + k
    const int b = bk >> 7;              // K = 128
    const int t = threadIdx.x;
    const float* tp = tgt + (size_t)b * M * 3;

    const float cx = cp[bk * 3 + 0], cy = cp[bk * 3 + 1], cz = cp[bk * 3 + 2];
    const float cp2 = cx * cx + cy * cy + cz * cz;

    unsigned long long best = ~0ull;
#pragma unroll 4
    for (int m = t; m < M; m += 256) {
        float tx = tp[m * 3 + 0], ty = tp[m * 3 + 1], tz = tp[m * 3 + 2];
        float tg2 = tx * tx + ty * ty + tz * tz;
        float cross = cx * tx + cy * ty + cz * tz;
        float v = (cp2 + tg2) - 2.0f * cross;
        unsigned int fb = __float_as_uint(v);
        fb = (fb & 0x80000000u) ? ~fb : (fb | 0x80000000u); // order-preserving flip
        unsigned long long pk = (((unsigned long long)fb) << 32) | (unsigned int)m;
        best = (pk < best) ? pk : best;   // min value, tie -> smaller m
    }
#pragma unroll
    for (int off = 32; off >= 1; off >>= 1) {
        unsigned long long o = shfl_down_u64(best, off);
        best = (o < best) ? o : best;
    }
    __shared__ unsigned long long red[4];
    __shared__ int snn;
    if ((t & 63) == 0) red[t >> 6] = best;
    __syncthreads();
    if (t == 0) {
        unsigned long long bb = red[0];
        for (int wv = 1; wv < 4; ++wv) bb = (red[wv] < bb) ? red[wv] : bb;
        snn = (int)(bb & 0xFFFFFFFFull);
    }
    __syncthreads();
    const int nn = snn;

    const float4* a = reinterpret_cast<const float4*>(
        src_feats + ((size_t)b * N + cp_idx[bk]) * F);
    const float4* c = reinterpret_cast<const float4*>(
        tgt_feats + ((size_t)b * M + nn) * F);
    unsigned short* o = mlp_b + (size_t)bk * 2 * F;
    float4 av = a[t];
    float4 cv = c[t];
    ushort4 a4, c4;
    a4.x = f2bf(av.x); a4.y = f2bf(av.y); a4.z = f2bf(av.z); a4.w = f2bf(av.w);
    c4.x = f2bf(cv.x); c4.y = f2bf(cv.y); c4.z = f2bf(cv.z); c4.w = f2bf(cv.w);
    *reinterpret_cast<ushort4*>(&o[t * 4]) = a4;            // cols [0,1024)
    *reinterpret_cast<ushort4*>(&o[F + t * 4]) = c4;        // cols [1024,2048)
}

// ---------------------------------------------------------------------------
// 3. bf16 MFMA GEMM + bias + fused column sum/sumsq stats.
//    C(MxN f32) = A(MxK bf16, row-major) @ Bt(NxK bf16, transposed) + bias.
//    64x64 tile, 256 threads (4 waves), mfma_f32_16x16x32_bf16.
// ---------------------------------------------------------------------------
__global__ __launch_bounds__(256) void gemm_mfma_stats(
        const unsigned short* __restrict__ A, const unsigned short* __restrict__ Bt,
        const float* __restrict__ bias, float* __restrict__ C,
        float* __restrict__ psum, float* __restrict__ psumsq,
        int M, int N, int K) {
    __shared__ __align__(16) unsigned short As[64][72];
    __shared__ __align__(16) unsigned short Bs[64][72];
    __shared__ float sS[64], sSS[64];
    const int tid = threadIdx.x;
    const int w = tid >> 6, l = tid & 63;
    const int m0 = blockIdx.y * 64, n0 = blockIdx.x * 64;

    f32x4 acc[4];
#pragma unroll
    for (int nt = 0; nt < 4; ++nt) acc[nt] = (f32x4){0.f, 0.f, 0.f, 0.f};

    const int lr = l & 15;        // row/col within 16-tile
    const int lg = l >> 4;        // k-group 0..3

    for (int kt = 0; kt < K; kt += 64) {
        __syncthreads();
#pragma unroll
        for (int s = 0; s < 2; ++s) {
            int u = tid + s * 256;
            int row = u >> 3, kc = (u & 7) * 8;
            *reinterpret_cast<uint4*>(&As[row][kc]) =
                *reinterpret_cast<const uint4*>(&A[(size_t)(m0 + row) * K + kt + kc]);
            *reinterpret_cast<uint4*>(&Bs[row][kc]) =
                *reinterpret_cast<const uint4*>(&Bt[(size_t)(n0 + row) * K + kt + kc]);
        }
        __syncthreads();
#pragma unroll
        for (int kf = 0; kf < 2; ++kf) {
            bf16x8 af = *reinterpret_cast<const bf16x8*>(&As[w * 16 + lr][kf * 32 + lg * 8]);
#pragma unroll
            for (int nt = 0; nt < 4; ++nt) {
                bf16x8 bfr = *reinterpret_cast<const bf16x8*>(&Bs[nt * 16 + lr][kf * 32 + lg * 8]);
                acc[nt] = __builtin_amdgcn_mfma_f32_16x16x32_bf16(af, bfr, acc[nt], 0, 0, 0);
            }
        }
    }

    // epilogue: bias add, C store, column stats
    if (tid < 64) { sS[tid] = 0.f; sSS[tid] = 0.f; }
    __syncthreads();
#pragma unroll
    for (int nt = 0; nt < 4; ++nt) {
        const int col = n0 + nt * 16 + lr;
        const float bv = bias[col];
        float s = 0.f, ss = 0.f;
#pragma unroll
        for (int r = 0; r < 4; ++r) {
            const int row = m0 + w * 16 + lg * 4 + r;     // C/D: row=(lane>>4)*4+reg
            float v = acc[nt][r] + bv;
            C[(size_t)row * N + col] = v;
            s += v; ss += v * v;
        }
        s += __shfl_xor(s, 16, 64); ss += __shfl_xor(ss, 16, 64);
        s += __shfl_xor(s, 32, 64); ss += __shfl_xor(ss, 32, 64);
        if (lg == 0) {                                     // lanes 0..15 of each wave
            atomicAdd(&sS[nt * 16 + lr], s);
            atomicAdd(&sSS[nt * 16 + lr], ss);
        }
    }
    __syncthreads();
    if (tid < 64) {
        atomicAdd(&psum[n0 + tid], sS[tid]);
        atomicAdd(&psumsq[n0 + tid], sSS[tid]);
    }
}

// ---------------------------------------------------------------------------
// 4. BN apply + ReLU: h1 (f32) -> h1b (bf16) for layer-2 GEMM
// ---------------------------------------------------------------------------
__global__ __launch_bounds__(256) void bn_apply_bf16(
        const float* __restrict__ Hm, const float* __restrict__ psum,
        const float* __restrict__ psumsq, const float* __restrict__ g,
        const float* __restrict__ beta, unsigned short* __restrict__ out,
        float invM) {
    const int i = (blockIdx.x * 256 + threadIdx.x) * 4;
    float4 x = *reinterpret_cast<const float4*>(&Hm[i]);
    const int c = i & 511;                 // H = 512
    ushort4 o4;
    float xv[4] = {x.x, x.y, x.z, x.w};
    unsigned short ov[4];
#pragma unroll
    for (int j = 0; j < 4; ++j) {
        const int col = c + j;
        const float m = psum[col] * invM;
        const float var = fmaxf(psumsq[col] * invM - m * m, 0.f);
        const float rs = rsqrtf(var + 1e-5f);
        float h = fmaxf(g[col] * (xv[j] - m) * rs + beta[col], 0.f);
        ov[j] = f2bf(h);
    }
    o4.x = ov[0]; o4.y = ov[1]; o4.z = ov[2]; o4.w = ov[3];
    *reinterpret_cast<ushort4*>(&out[i]) = o4;
}

// ---------------------------------------------------------------------------
// 5. Fused BN2 + head: w (1024x3) = relu(bn(h2)) @ W3 + b3 ; one block per row
// ---------------------------------------------------------------------------
__global__ __launch_bounds__(256) void bn_head(
        const float* __restrict__ H2, const float* __restrict__ psum,
        const float* __restrict__ psumsq, const float* __restrict__ g,
        const float* __restrict__ beta, const float* __restrict__ W3,
        const float* __restrict__ b3, float* __restrict__ w_out,
        int Ncols, float invM) {
    const int r = blockIdx.x;
    const int t = threadIdx.x;
    float a0 = 0.f, a1 = 0.f, a2 = 0.f;
    for (int c = t; c < Ncols; c += 256) {
        const float m = psum[c] * invM;
        const float var = fmaxf(psumsq[c] * invM - m * m, 0.f);
        const float rs = rsqrtf(var + 1e-5f);
        float x = H2[(size_t)r * Ncols + c];
        float h = fmaxf(g[c] * (x - m) * rs + beta[c], 0.f);
        a0 += h * W3[c * 3 + 0];
        a1 += h * W3[c * 3 + 1];
        a2 += h * W3[c * 3 + 2];
    }
#pragma unroll
    for (int off = 32; off >= 1; off >>= 1) {
        a0 += __shfl_down(a0, off, 64);
        a1 += __shfl_down(a1, off, 64);
        a2 += __shfl_down(a2, off, 64);
    }
    __shared__ float red[4][3];
    if ((t & 63) == 0) {
        red[t >> 6][0] = a0; red[t >> 6][1] = a1; red[t >> 6][2] = a2;
    }
    __syncthreads();
    if (t == 0) {
        float s0 = red[0][0] + red[1][0] + red[2][0] + red[3][0];
        float s1 = red[0][1] + red[1][1] + red[2][1] + red[3][1];
        float s2 = red[0][2] + red[1][2] + red[2][2] + red[3][2];
        w_out[r * 3 + 0] = s0 + b3[0];
        w_out[r * 3 + 1] = s1 + b3[1];
        w_out[r * 3 + 2] = s2 + b3[2];
    }
}

// ---------------------------------------------------------------------------
// 6. RBF softmax interpolation: output = src + (softmax(-2*d2) @ w)
// ---------------------------------------------------------------------------
__global__ __launch_bounds__(256) void rbf_kernel(
        const float* __restrict__ src, const float* __restrict__ cp,
        const float* __restrict__ w, float* __restrict__ outp,
        float* __restrict__ delta, int N, int K) {
    __shared__ float scx[128], scy[128], scz[128];
    __shared__ float swx[128], swy[128], swz[128];
    const int b = blockIdx.x >> 6;      // 64 chunks of 256 per batch
    const int chunk = blockIdx.x & 63;
    const int t = threadIdx.x;
    if (t < K) {
        const int base = (b * K + t) * 3;
        scx[t] = cp[base + 0]; scy[t] = cp[base + 1]; scz[t] = cp[base + 2];
        swx[t] = w[base + 0];  swy[t] = w[base + 1];  swz[t] = w[base + 2];
    }
    __syncthreads();

    const int n = chunk * 256 + t;
    const size_t pbase = ((size_t)b * N + n) * 3;
    const float x = src[pbase + 0], y = src[pbase + 1], z = src[pbase + 2];

    float mind = __builtin_huge_valf();
    for (int k = 0; k < K; ++k) {
        float dx = x - scx[k], dy = y - scy[k], dz = z - scz[k];
        float d2 = dx * dx + dy * dy + dz * dz;
        mind = fminf(mind, d2);
    }
    float sum = 0.f, ax = 0.f, ay = 0.f, az = 0.f;
    for (int k = 0; k < K; ++k) {
        float dx = x - scx[k], dy = y - scy[k], dz = z - scz[k];
        float d2 = dx * dx + dy * dy + dz * dz;
        float e = __expf(2.0f * (mind - d2));   // softmax(-2*d2), max-subtracted
        sum += e;
        ax += e * swx[k]; ay += e * swy[k]; az += e * swz[k];
    }
    const float inv = 1.0f / sum;
    ax *= inv; ay *= inv; az *= inv;
    delta[pbase + 0] = ax; delta[pbase + 1] = ay; delta[pbase + 2] = az;
    outp[pbase + 0] = x + ax; outp[pbase + 1] = y + ay; outp[pbase + 2] = z + az;
}

// ---------------------------------------------------------------------------
// launch
// ---------------------------------------------------------------------------
extern "C" void kernel_launch(void* const* d_in, const int* in_sizes, int n_in,
                              void* d_out, int out_size, void* d_ws, size_t ws_size,
                              hipStream_t stream) {
    const int B = 8, N = 16384, M = 16384, F = 1024, H = 512, K = 128;
    const int BK = B * K;               // 1024 MLP rows

    const float* src       = (const float*)d_in[0];
    const float* ppf       = (const float*)d_in[1];
    const float* tgt       = (const float*)d_in[2];
    const float* tpf       = (const float*)d_in[3];
    const float* W1        = (const float*)d_in[4];
    const float* b1        = (const float*)d_in[5];
    const float* g1        = (const float*)d_in[6];
    const float* beta1     = (const float*)d_in[7];
    const float* W2        = (const float*)d_in[8];
    const float* b2        = (const float*)d_in[9];
    const float* g2        = (const float*)d_in[10];
    const float* beta2     = (const float*)d_in[11];
    const float* W3        = (const float*)d_in[12];
    const float* b3        = (const float*)d_in[13];

    float* out_output = (float*)d_out;                       // B*N*3
    float* out_delta  = out_output + (size_t)B * N * 3;      // B*N*3
    float* out_cp     = out_delta + (size_t)B * N * 3;       // B*K*3
    float* out_w      = out_cp + (size_t)B * K * 3;          // B*K*3

    char* ws = (char*)d_ws;
    int*            cp_idx = (int*)(ws + 0);                 // 4 KB
    float*          stats  = (float*)(ws + 4096);            // 2048 floats (8 KB)
    float* psum1   = stats;
    float* psumsq1 = stats + 512;
    float* psum2   = stats + 1024;
    float* psumsq2 = stats + 1536;
    unsigned short* mlp_b  = (unsigned short*)(ws + 16384);       // 1024x2048 bf16 (4 MB)
    unsigned short* W1t    = (unsigned short*)(ws + 4210688);     // 512x2048 bf16 (2 MB)
    unsigned short* W2t    = (unsigned short*)(ws + 6307840);     // 512x512 bf16 (512 KB)
    float*          h1     = (float*)(ws + 6832128);              // 1024x512 f32 (2 MB)
    unsigned short* h1b    = (unsigned short*)(ws + 8929280);     // 1024x512 bf16 (1 MB)
    float*          h2     = (float*)(ws + 9977856);              // 1024x512 f32 (2 MB)

    // 1. FPS + weight convert/transpose + stats zero
    fps_conv_kernel<<<8 + CONV_BLOCKS, FPS_THREADS, 0, stream>>>(
        src, cp_idx, out_cp, W1, W2, W1t, W2t, stats, N, K);
    // 2. fused nearest-target + gather (bf16)
    nn_gather<<<BK, 256, 0, stream>>>(tgt, out_cp, cp_idx, ppf, tpf, mlp_b, N, M, F);
    // 3. layer 1: MFMA GEMM + bias + stats
    gemm_mfma_stats<<<dim3(H / 64, BK / 64), 256, 0, stream>>>(
        mlp_b, W1t, b1, h1, psum1, psumsq1, BK, H, 2 * F);
    // 4. BN1 apply -> bf16
    bn_apply_bf16<<<(BK * H / 4) / 256, 256, 0, stream>>>(
        h1, psum1, psumsq1, g1, beta1, h1b, 1.0f / BK);
    // 5. layer 2: MFMA GEMM + bias + stats
    gemm_mfma_stats<<<dim3(H / 64, BK / 64), 256, 0, stream>>>(
        h1b, W2t, b2, h2, psum2, psumsq2, BK, H, H);
    // 6. fused BN2 + head -> w
    bn_head<<<BK, 256, 0, stream>>>(
        h2, psum2, psumsq2, g2, beta2, W3, b3, out_w, H, 1.0f / BK);
    // 7. RBF interpolation -> output, delta
    rbf_kernel<<<B * (N / 256), 256, 0, stream>>>(src, out_cp, out_w, out_output, out_delta, N, K);
}

// Round 6
// 322.811 us; speedup vs baseline: 1.5453x; 1.1457x over previous
//
#include <hip/hip_runtime.h>
#include <hip/hip_bf16.h>

#define FPS_THREADS 1024
#define PTS_PER_THR 16      // 16384 / 1024
#define CONV_BLOCKS 120

typedef __attribute__((ext_vector_type(8))) short bf16x8;
typedef __attribute__((ext_vector_type(4))) float f32x4;

// ---------------------------------------------------------------------------
// helpers
// ---------------------------------------------------------------------------
__device__ inline unsigned long long shfl_down_u64(unsigned long long x, int off) {
    unsigned int lo = (unsigned int)(x & 0xFFFFFFFFull);
    unsigned int hi = (unsigned int)(x >> 32);
    lo = __shfl_down(lo, off, 64);
    hi = __shfl_down(hi, off, 64);
    return (((unsigned long long)hi) << 32) | lo;
}

__device__ inline unsigned short f2bf(float x) {
    union { float f; unsigned int u; } v; v.f = x;
    unsigned int r = v.u + 0x7FFFu + ((v.u >> 16) & 1u);   // round-to-nearest-even
    return (unsigned short)(r >> 16);
}

// rocPRIM-style 64-lane max via DPP: row_shr 1/2/4/8 + row_bcast 15/31.
// Only lane 63 holds the full max afterwards; read it with readlane.
__device__ inline float wave_max_dpp(float v) {
    int w = __float_as_int(v);
#define DPP_MAX_STEP(ctrl, rmask)                                             \
    {                                                                         \
        int _t = __builtin_amdgcn_update_dpp(w, w, ctrl, rmask, 0xf, false);  \
        w = __float_as_int(fmaxf(__int_as_float(w), __int_as_float(_t)));     \
    }
    DPP_MAX_STEP(0x111, 0xf)   // row_shr:1
    DPP_MAX_STEP(0x112, 0xf)   // row_shr:2
    DPP_MAX_STEP(0x114, 0xf)   // row_shr:4
    DPP_MAX_STEP(0x118, 0xf)   // row_shr:8  -> lane15/31/47/63 = row max
    DPP_MAX_STEP(0x142, 0xa)   // row_bcast:15 -> rows 1,3
    DPP_MAX_STEP(0x143, 0xc)   // row_bcast:31 -> rows 2,3; lane63 = wave max
#undef DPP_MAX_STEP
    return __int_as_float(__builtin_amdgcn_readlane(w, 63));
}

// ---------------------------------------------------------------------------
// 1. FPS (blocks 0..7, one per batch) + weight transpose/convert + stats zero
//    (blocks 8..127, runs in the shadow of the serial FPS).
//
//    Per iteration: per-thread (tmax,jbest) argmax with strict > (first max =
//    smallest index, matching numpy); wave max via DPP (~50 cyc vs ~720 for
//    bpermute shuffles); every lane with tmax==wavemax publishes packed
//    (value || ~j) via one LDS atomicMax (order-independent, tie -> smaller
//    j). 3-slot rotating cell makes the reset race-free.
// ---------------------------------------------------------------------------
__global__ __launch_bounds__(FPS_THREADS) void fps_conv_kernel(
        const float* __restrict__ src, int* __restrict__ cp_idx,
        float* __restrict__ out_cp,
        const float* __restrict__ W1, const float* __restrict__ W2,
        unsigned short* __restrict__ W1t, unsigned short* __restrict__ W2t,
        float* __restrict__ stats, int N, int K) {
    const int t = threadIdx.x;
    if (blockIdx.x >= 8) {
        const int cb = blockIdx.x - 8;
        if (cb == 0) { stats[t] = 0.f; stats[t + 1024] = 0.f; }  // 2048 floats
        // W1t[n][k] = bf16(W1[k][n]);  W1: (2048, 512)
        for (size_t idx = (size_t)cb * 1024 + t; idx < (size_t)2048 * 512;
             idx += (size_t)CONV_BLOCKS * 1024) {
            int k = (int)(idx >> 9), n = (int)(idx & 511);
            W1t[(size_t)n * 2048 + k] = f2bf(W1[idx]);
        }
        // W2t[n][k] = bf16(W2[k][n]);  W2: (512, 512)
        for (size_t idx = (size_t)cb * 1024 + t; idx < (size_t)512 * 512;
             idx += (size_t)CONV_BLOCKS * 1024) {
            int k = (int)(idx >> 9), n = (int)(idx & 511);
            W2t[(size_t)n * 512 + k] = f2bf(W2[idx]);
        }
        return;
    }

    const int b = blockIdx.x;
    const float* p = src + (size_t)b * N * 3;

    float px[PTS_PER_THR], py[PTS_PER_THR], pz[PTS_PER_THR], dmin[PTS_PER_THR];
#pragma unroll
    for (int i = 0; i < PTS_PER_THR; ++i) {
        int j = i * FPS_THREADS + t;
        px[i] = p[j * 3 + 0];
        py[i] = p[j * 3 + 1];
        pz[i] = p[j * 3 + 2];
        dmin[i] = __builtin_huge_valf();
    }

    __shared__ unsigned long long slot[3];
    if (t == 0) { slot[0] = 0ull; slot[1] = 0ull; slot[2] = 0ull; }
    __syncthreads();

    int far = 0;
    int cur = 0;
    for (int k = 0;; ++k) {
        const float cx = p[far * 3 + 0];
        const float cy = p[far * 3 + 1];
        const float cz = p[far * 3 + 2];
        if (t == 0) {
            cp_idx[b * K + k] = far;
            out_cp[(b * K + k) * 3 + 0] = cx;
            out_cp[(b * K + k) * 3 + 1] = cy;
            out_cp[(b * K + k) * 3 + 2] = cz;
        }
        if (k == K - 1) break;

        // update dmin; per-thread argmax (strict > keeps first = smallest j)
        float tmax = -1.0f;
        int jbest = 0;
#pragma unroll
        for (int i = 0; i < PTS_PER_THR; ++i) {
            float dx = px[i] - cx, dy = py[i] - cy, dz = pz[i] - cz;
            float d = dx * dx + dy * dy + dz * dz;
            float dm = fminf(dmin[i], d);
            dmin[i] = dm;
            bool c = dm > tmax;
            tmax = c ? dm : tmax;
            jbest = c ? (i * FPS_THREADS + t) : jbest;
        }

        // wave max via DPP; winning lane(s) publish directly to the block slot
        const float wmax = wave_max_dpp(tmax);
        if (tmax == wmax) {
            unsigned long long pk =
                (((unsigned long long)__float_as_uint(wmax)) << 32) |
                (unsigned long long)(0xFFFFFFFFu - (unsigned int)jbest);
            atomicMax(&slot[cur], pk);
        }
        const int nxt = (cur == 2) ? 0 : cur + 1;
        if (t == 0) slot[nxt] = 0ull;   // reset for iteration k+1 (safe: last
                                        // read of this slot was in iter k-2)
        __syncthreads();
        unsigned long long bb = slot[cur];
        far = (int)(0xFFFFFFFFu - (unsigned int)(bb & 0xFFFFFFFFull));
        cur = nxt;
    }
}

// ---------------------------------------------------------------------------
// 2. Fused: nearest target per control point + gather MLP input row (bf16).
// ---------------------------------------------------------------------------
__global__ __launch_bounds__(256) void nn_gather(
        const float* __restrict__ tgt, const float* __restrict__ cp,
        const int* __restrict__ cp_idx,
        const float* __restrict__ src_feats, const float* __restrict__ tgt_feats,
        unsigned short* __restrict__ mlp_b, int N, int M, int F) {
    const int bk = blockIdx.x;          // b*K + k
    const int b = bk >> 7;              // K = 128
    const int t = threadIdx.x;
    const float* tp = tgt + (size_t)b * M * 3;

    const float cx = cp[bk * 3 + 0], cy = cp[bk * 3 + 1], cz = cp[bk * 3 + 2];
    const float cp2 = cx * cx + cy * cy + cz * cz;

    unsigned long long best = ~0ull;
#pragma unroll 4
    for (int m = t; m < M; m += 256) {
        float tx = tp[m * 3 + 0], ty = tp[m * 3 + 1], tz = tp[m * 3 + 2];
        float tg2 = tx * tx + ty * ty + tz * tz;
        float cross = cx * tx + cy * ty + cz * tz;
        float v = (cp2 + tg2) - 2.0f * cross;
        unsigned int fb = __float_as_uint(v);
        fb = (fb & 0x80000000u) ? ~fb : (fb | 0x80000000u); // order-preserving flip
        unsigned long long pk = (((unsigned long long)fb) << 32) | (unsigned int)m;
        best = (pk < best) ? pk : best;   // min value, tie -> smaller m
    }
#pragma unroll
    for (int off = 32; off >= 1; off >>= 1) {
        unsigned long long o = shfl_down_u64(best, off);
        best = (o < best) ? o : best;
    }
    __shared__ unsigned long long red[4];
    __shared__ int snn;
    if ((t & 63) == 0) red[t >> 6] = best;
    __syncthreads();
    if (t == 0) {
        unsigned long long bb = red[0];
        for (int wv = 1; wv < 4; ++wv) bb = (red[wv] < bb) ? red[wv] : bb;
        snn = (int)(bb & 0xFFFFFFFFull);
    }
    __syncthreads();
    const int nn = snn;

    const float4* a = reinterpret_cast<const float4*>(
        src_feats + ((size_t)b * N + cp_idx[bk]) * F);
    const float4* c = reinterpret_cast<const float4*>(
        tgt_feats + ((size_t)b * M + nn) * F);
    unsigned short* o = mlp_b + (size_t)bk * 2 * F;
    float4 av = a[t];
    float4 cv = c[t];
    ushort4 a4, c4;
    a4.x = f2bf(av.x); a4.y = f2bf(av.y); a4.z = f2bf(av.z); a4.w = f2bf(av.w);
    c4.x = f2bf(cv.x); c4.y = f2bf(cv.y); c4.z = f2bf(cv.z); c4.w = f2bf(cv.w);
    *reinterpret_cast<ushort4*>(&o[t * 4]) = a4;            // cols [0,1024)
    *reinterpret_cast<ushort4*>(&o[F + t * 4]) = c4;        // cols [1024,2048)
}

// ---------------------------------------------------------------------------
// 3. bf16 MFMA GEMM + bias + fused column sum/sumsq stats.
//    C(MxN f32) = A(MxK bf16, row-major) @ Bt(NxK bf16, transposed) + bias.
//    64x64 tile, 256 threads (4 waves), mfma_f32_16x16x32_bf16.
// ---------------------------------------------------------------------------
__global__ __launch_bounds__(256) void gemm_mfma_stats(
        const unsigned short* __restrict__ A, const unsigned short* __restrict__ Bt,
        const float* __restrict__ bias, float* __restrict__ C,
        float* __restrict__ psum, float* __restrict__ psumsq,
        int M, int N, int K) {
    __shared__ __align__(16) unsigned short As[64][72];
    __shared__ __align__(16) unsigned short Bs[64][72];
    __shared__ float sS[64], sSS[64];
    const int tid = threadIdx.x;
    const int w = tid >> 6, l = tid & 63;
    const int m0 = blockIdx.y * 64, n0 = blockIdx.x * 64;

    f32x4 acc[4];
#pragma unroll
    for (int nt = 0; nt < 4; ++nt) acc[nt] = (f32x4){0.f, 0.f, 0.f, 0.f};

    const int lr = l & 15;        // row/col within 16-tile
    const int lg = l >> 4;        // k-group 0..3

    for (int kt = 0; kt < K; kt += 64) {
        __syncthreads();
#pragma unroll
        for (int s = 0; s < 2; ++s) {
            int u = tid + s * 256;
            int row = u >> 3, kc = (u & 7) * 8;
            *reinterpret_cast<uint4*>(&As[row][kc]) =
                *reinterpret_cast<const uint4*>(&A[(size_t)(m0 + row) * K + kt + kc]);
            *reinterpret_cast<uint4*>(&Bs[row][kc]) =
                *reinterpret_cast<const uint4*>(&Bt[(size_t)(n0 + row) * K + kt + kc]);
        }
        __syncthreads();
#pragma unroll
        for (int kf = 0; kf < 2; ++kf) {
            bf16x8 af = *reinterpret_cast<const bf16x8*>(&As[w * 16 + lr][kf * 32 + lg * 8]);
#pragma unroll
            for (int nt = 0; nt < 4; ++nt) {
                bf16x8 bfr = *reinterpret_cast<const bf16x8*>(&Bs[nt * 16 + lr][kf * 32 + lg * 8]);
                acc[nt] = __builtin_amdgcn_mfma_f32_16x16x32_bf16(af, bfr, acc[nt], 0, 0, 0);
            }
        }
    }

    // epilogue: bias add, C store, column stats
    if (tid < 64) { sS[tid] = 0.f; sSS[tid] = 0.f; }
    __syncthreads();
#pragma unroll
    for (int nt = 0; nt < 4; ++nt) {
        const int col = n0 + nt * 16 + lr;
        const float bv = bias[col];
        float s = 0.f, ss = 0.f;
#pragma unroll
        for (int r = 0; r < 4; ++r) {
            const int row = m0 + w * 16 + lg * 4 + r;     // C/D: row=(lane>>4)*4+reg
            float v = acc[nt][r] + bv;
            C[(size_t)row * N + col] = v;
            s += v; ss += v * v;
        }
        s += __shfl_xor(s, 16, 64); ss += __shfl_xor(ss, 16, 64);
        s += __shfl_xor(s, 32, 64); ss += __shfl_xor(ss, 32, 64);
        if (lg == 0) {                                     // lanes 0..15 of each wave
            atomicAdd(&sS[nt * 16 + lr], s);
            atomicAdd(&sSS[nt * 16 + lr], ss);
        }
    }
    __syncthreads();
    if (tid < 64) {
        atomicAdd(&psum[n0 + tid], sS[tid]);
        atomicAdd(&psumsq[n0 + tid], sSS[tid]);
    }
}

// ---------------------------------------------------------------------------
// 4. BN apply + ReLU: h1 (f32) -> h1b (bf16) for layer-2 GEMM
// ---------------------------------------------------------------------------
__global__ __launch_bounds__(256) void bn_apply_bf16(
        const float* __restrict__ Hm, const float* __restrict__ psum,
        const float* __restrict__ psumsq, const float* __restrict__ g,
        const float* __restrict__ beta, unsigned short* __restrict__ out,
        float invM) {
    const int i = (blockIdx.x * 256 + threadIdx.x) * 4;
    float4 x = *reinterpret_cast<const float4*>(&Hm[i]);
    const int c = i & 511;                 // H = 512
    ushort4 o4;
    float xv[4] = {x.x, x.y, x.z, x.w};
    unsigned short ov[4];
#pragma unroll
    for (int j = 0; j < 4; ++j) {
        const int col = c + j;
        const float m = psum[col] * invM;
        const float var = fmaxf(psumsq[col] * invM - m * m, 0.f);
        const float rs = rsqrtf(var + 1e-5f);
        float h = fmaxf(g[col] * (xv[j] - m) * rs + beta[col], 0.f);
        ov[j] = f2bf(h);
    }
    o4.x = ov[0]; o4.y = ov[1]; o4.z = ov[2]; o4.w = ov[3];
    *reinterpret_cast<ushort4*>(&out[i]) = o4;
}

// ---------------------------------------------------------------------------
// 5. Fused BN2 + head: w (1024x3) = relu(bn(h2)) @ W3 + b3 ; one block per row
// ---------------------------------------------------------------------------
__global__ __launch_bounds__(256) void bn_head(
        const float* __restrict__ H2, const float* __restrict__ psum,
        const float* __restrict__ psumsq, const float* __restrict__ g,
        const float* __restrict__ beta, const float* __restrict__ W3,
        const float* __restrict__ b3, float* __restrict__ w_out,
        int Ncols, float invM) {
    const int r = blockIdx.x;
    const int t = threadIdx.x;
    float a0 = 0.f, a1 = 0.f, a2 = 0.f;
    for (int c = t; c < Ncols; c += 256) {
        const float m = psum[c] * invM;
        const float var = fmaxf(psumsq[c] * invM - m * m, 0.f);
        const float rs = rsqrtf(var + 1e-5f);
        float x = H2[(size_t)r * Ncols + c];
        float h = fmaxf(g[c] * (x - m) * rs + beta[c], 0.f);
        a0 += h * W3[c * 3 + 0];
        a1 += h * W3[c * 3 + 1];
        a2 += h * W3[c * 3 + 2];
    }
#pragma unroll
    for (int off = 32; off >= 1; off >>= 1) {
        a0 += __shfl_down(a0, off, 64);
        a1 += __shfl_down(a1, off, 64);
        a2 += __shfl_down(a2, off, 64);
    }
    __shared__ float red[4][3];
    if ((t & 63) == 0) {
        red[t >> 6][0] = a0; red[t >> 6][1] = a1; red[t >> 6][2] = a2;
    }
    __syncthreads();
    if (t == 0) {
        float s0 = red[0][0] + red[1][0] + red[2][0] + red[3][0];
        float s1 = red[0][1] + red[1][1] + red[2][1] + red[3][1];
        float s2 = red[0][2] + red[1][2] + red[2][2] + red[3][2];
        w_out[r * 3 + 0] = s0 + b3[0];
        w_out[r * 3 + 1] = s1 + b3[1];
        w_out[r * 3 + 2] = s2 + b3[2];
    }
}

// ---------------------------------------------------------------------------
// 6. RBF softmax interpolation: output = src + (softmax(-2*d2) @ w)
// ---------------------------------------------------------------------------
__global__ __launch_bounds__(256) void rbf_kernel(
        const float* __restrict__ src, const float* __restrict__ cp,
        const float* __restrict__ w, float* __restrict__ outp,
        float* __restrict__ delta, int N, int K) {
    __shared__ float scx[128], scy[128], scz[128];
    __shared__ float swx[128], swy[128], swz[128];
    const int b = blockIdx.x >> 6;      // 64 chunks of 256 per batch
    const int chunk = blockIdx.x & 63;
    const int t = threadIdx.x;
    if (t < K) {
        const int base = (b * K + t) * 3;
        scx[t] = cp[base + 0]; scy[t] = cp[base + 1]; scz[t] = cp[base + 2];
        swx[t] = w[base + 0];  swy[t] = w[base + 1];  swz[t] = w[base + 2];
    }
    __syncthreads();

    const int n = chunk * 256 + t;
    const size_t pbase = ((size_t)b * N + n) * 3;
    const float x = src[pbase + 0], y = src[pbase + 1], z = src[pbase + 2];

    float mind = __builtin_huge_valf();
    for (int k = 0; k < K; ++k) {
        float dx = x - scx[k], dy = y - scy[k], dz = z - scz[k];
        float d2 = dx * dx + dy * dy + dz * dz;
        mind = fminf(mind, d2);
    }
    float sum = 0.f, ax = 0.f, ay = 0.f, az = 0.f;
    for (int k = 0; k < K; ++k) {
        float dx = x - scx[k], dy = y - scy[k], dz = z - scz[k];
        float d2 = dx * dx + dy * dy + dz * dz;
        float e = __expf(2.0f * (mind - d2));   // softmax(-2*d2), max-subtracted
        sum += e;
        ax += e * swx[k]; ay += e * swy[k]; az += e * swz[k];
    }
    const float inv = 1.0f / sum;
    ax *= inv; ay *= inv; az *= inv;
    delta[pbase + 0] = ax; delta[pbase + 1] = ay; delta[pbase + 2] = az;
    outp[pbase + 0] = x + ax; outp[pbase + 1] = y + ay; outp[pbase + 2] = z + az;
}

// ---------------------------------------------------------------------------
// launch
// ---------------------------------------------------------------------------
extern "C" void kernel_launch(void* const* d_in, const int* in_sizes, int n_in,
                              void* d_out, int out_size, void* d_ws, size_t ws_size,
                              hipStream_t stream) {
    const int B = 8, N = 16384, M = 16384, F = 1024, H = 512, K = 128;
    const int BK = B * K;               // 1024 MLP rows

    const float* src       = (const float*)d_in[0];
    const float* ppf       = (const float*)d_in[1];
    const float* tgt       = (const float*)d_in[2];
    const float* tpf       = (const float*)d_in[3];
    const float* W1        = (const float*)d_in[4];
    const float* b1        = (const float*)d_in[5];
    const float* g1        = (const float*)d_in[6];
    const float* beta1     = (const float*)d_in[7];
    const float* W2        = (const float*)d_in[8];
    const float* b2        = (const float*)d_in[9];
    const float* g2        = (const float*)d_in[10];
    const float* beta2     = (const float*)d_in[11];
    const float* W3        = (const float*)d_in[12];
    const float* b3        = (const float*)d_in[13];

    float* out_output = (float*)d_out;                       // B*N*3
    float* out_delta  = out_output + (size_t)B * N * 3;      // B*N*3
    float* out_cp     = out_delta + (size_t)B * N * 3;       // B*K*3
    float* out_w      = out_cp + (size_t)B * K * 3;          // B*K*3

    char* ws = (char*)d_ws;
    int*            cp_idx = (int*)(ws + 0);                 // 4 KB
    float*          stats  = (float*)(ws + 4096);            // 2048 floats (8 KB)
    float* psum1   = stats;
    float* psumsq1 = stats + 512;
    float* psum2   = stats + 1024;
    float* psumsq2 = stats + 1536;
    unsigned short* mlp_b  = (unsigned short*)(ws + 16384);       // 1024x2048 bf16 (4 MB)
    unsigned short* W1t    = (unsigned short*)(ws + 4210688);     // 512x2048 bf16 (2 MB)
    unsigned short* W2t    = (unsigned short*)(ws + 6307840);     // 512x512 bf16 (512 KB)
    float*          h1     = (float*)(ws + 6832128);              // 1024x512 f32 (2 MB)
    unsigned short* h1b    = (unsigned short*)(ws + 8929280);     // 1024x512 bf16 (1 MB)
    float*          h2     = (float*)(ws + 9977856);              // 1024x512 f32 (2 MB)

    // 1. FPS + weight convert/transpose + stats zero
    fps_conv_kernel<<<8 + CONV_BLOCKS, FPS_THREADS, 0, stream>>>(
        src, cp_idx, out_cp, W1, W2, W1t, W2t, stats, N, K);
    // 2. fused nearest-target + gather (bf16)
    nn_gather<<<BK, 256, 0, stream>>>(tgt, out_cp, cp_idx, ppf, tpf, mlp_b, N, M, F);
    // 3. layer 1: MFMA GEMM + bias + stats
    gemm_mfma_stats<<<dim3(H / 64, BK / 64), 256, 0, stream>>>(
        mlp_b, W1t, b1, h1, psum1, psumsq1, BK, H, 2 * F);
    // 4. BN1 apply -> bf16
    bn_apply_bf16<<<(BK * H / 4) / 256, 256, 0, stream>>>(
        h1, psum1, psumsq1, g1, beta1, h1b, 1.0f / BK);
    // 5. layer 2: MFMA GEMM + bias + stats
    gemm_mfma_stats<<<dim3(H / 64, BK / 64), 256, 0, stream>>>(
        h1b, W2t, b2, h2, psum2, psumsq2, BK, H, H);
    // 6. fused BN2 + head -> w
    bn_head<<<BK, 256, 0, stream>>>(
        h2, psum2, psumsq2, g2, beta2, W3, b3, out_w, H, 1.0f / BK);
    // 7. RBF interpolation -> output, delta
    rbf_kernel<<<B * (N / 256), 256, 0, stream>>>(src, out_cp, out_w, out_output, out_delta, N, K);
}